// Round 1
// baseline (1933.137 us; speedup 1.0000x reference)
//
#include <hip/hip_runtime.h>
#include <math.h>

#define DIM   1024
#define NH    16
#define HD    64
#define GRP   128
#define BB    2
#define TT    2048
#define MROWS (BB*TT)   // 4096

// ---------------- wave helpers (wave64) ----------------
__device__ inline float wave_max(float v){
    for(int off=32; off; off>>=1) v = fmaxf(v, __shfl_xor(v, off));
    return v;
}
__device__ inline float wave_sum(float v){
    for(int off=32; off; off>>=1) v += __shfl_xor(v, off);
    return v;
}

// ---------------- weight quantization ----------------
// One thread per group of 128. Mean emulates numpy's 8-accumulator pairwise
// sum (ref=np) to minimize round(w/ws) boundary flips.
__global__ void quant_w(const float* __restrict__ w, float* __restrict__ wq){
    int gidx = blockIdx.x*blockDim.x + threadIdx.x;   // 1024*8 = 8192 groups
    if (gidx >= DIM*(DIM/GRP)) return;
    const float* p = w + (size_t)gidx*GRP;
    float r[8];
    #pragma unroll
    for(int j=0;j<8;j++) r[j] = fabsf(p[j]);
    for(int i=8;i<GRP;i+=8){
        #pragma unroll
        for(int j=0;j<8;j++) r[j] += fabsf(p[i+j]);
    }
    float s = ((r[0]+r[1])+(r[2]+r[3]))+((r[4]+r[5])+(r[6]+r[7]));
    float ws = s/(float)GRP + 1e-5f;
    float* q = wq + (size_t)gidx*GRP;
    for(int i=0;i<GRP;i++){
        float t = rintf(p[i]/ws);
        t = fminf(fmaxf(t,-1.f),1.f);
        q[i] = t*ws;
    }
}

// ---------------- activation quantization ----------------
// One block (256 thr) per token row of 1024.
__global__ __launch_bounds__(256) void quant_x(const float* __restrict__ x, float* __restrict__ xq){
    int row = blockIdx.x;
    const float* p = x + (size_t)row*DIM;
    float*       q = xq + (size_t)row*DIM;
    int tid = threadIdx.x;
    float v[4];
    float m = 0.f;
    #pragma unroll
    for(int i=0;i<4;i++){ v[i] = p[tid + 256*i]; m = fmaxf(m, fabsf(v[i])); }
    m = wave_max(m);
    __shared__ float red[4];
    if ((tid&63)==0) red[tid>>6] = m;
    __syncthreads();
    m = fmaxf(fmaxf(red[0],red[1]), fmaxf(red[2],red[3]));
    float s = 127.f/(m+1e-5f);
    #pragma unroll
    for(int i=0;i<4;i++){
        float t = rintf(v[i]*s);
        t = fminf(fmaxf(t,-128.f),127.f);
        q[tid + 256*i] = t/s;   // true division to match reference
    }
}

// ---------------- fp32 GEMM: C[M,N] = A[M,K] * W[N,K]^T ----------------
#define BM 64
#define BN 64
#define BK 16
__global__ __launch_bounds__(256) void gemm_f32(const float* __restrict__ A,
                                                const float* __restrict__ W,
                                                float* __restrict__ C,
                                                int M, int N, int K){
    __shared__ float As[BK][BM+4];
    __shared__ float Bs[BK][BN+4];
    int tid = threadIdx.x;
    int m0 = blockIdx.y*BM, n0 = blockIdx.x*BN;
    int tx = tid & 15, ty = tid >> 4;
    int lk = tid & 15;        // k within tile
    int lr = tid >> 4;        // row group
    float acc[4][4] = {};
    for(int k0=0;k0<K;k0+=BK){
        #pragma unroll
        for(int i=0;i<4;i++){
            As[lk][lr+16*i] = A[(size_t)(m0+lr+16*i)*K + k0+lk];
            Bs[lk][lr+16*i] = W[(size_t)(n0+lr+16*i)*K + k0+lk];
        }
        __syncthreads();
        #pragma unroll
        for(int kk=0;kk<BK;kk++){
            float a[4],b[4];
            #pragma unroll
            for(int i=0;i<4;i++) a[i]=As[kk][ty*4+i];
            #pragma unroll
            for(int j=0;j<4;j++) b[j]=Bs[kk][tx*4+j];
            #pragma unroll
            for(int i=0;i<4;i++)
                #pragma unroll
                for(int j=0;j<4;j++) acc[i][j] += a[i]*b[j];
        }
        __syncthreads();
    }
    #pragma unroll
    for(int i=0;i<4;i++)
        #pragma unroll
        for(int j=0;j<4;j++)
            C[(size_t)(m0+ty*4+i)*N + n0+tx*4+j] = acc[i][j];
}

// ---------------- RoPE (interleaved pairs), in-place on q and k ----------------
__global__ void rope_k(float* __restrict__ qb, float* __restrict__ kb,
                       const float* __restrict__ cosb, const float* __restrict__ sinb){
    int idx = blockIdx.x*blockDim.x + threadIdx.x;   // MROWS * DIM/2 pairs
    if (idx >= MROWS*(DIM/2)) return;
    int bt = idx >> 9;          // / 512
    int r  = idx & 511;         // h*32 + p
    int p  = r & 31;
    int t  = bt & (TT-1);
    float c = cosb[t*32+p], s = sinb[t*32+p];
    size_t base = (size_t)bt*DIM + (r<<1);
    float q0=qb[base], q1=qb[base+1];
    qb[base]   = q0*c - q1*s;
    qb[base+1] = q0*s + q1*c;
    float k0=kb[base], k1=kb[base+1];
    kb[base]   = k0*c - k1*s;
    kb[base+1] = k0*s + k1*c;
}

// ---------------- flash-style causal attention ----------------
// block = 256 thr = 4 waves; each wave owns one query row (4 consecutive rows).
// Iterate 64-key tiles staged in LDS with online softmax.
__global__ __launch_bounds__(256) void attn_k(const float* __restrict__ qb,
                                              const float* __restrict__ kb,
                                              const float* __restrict__ vb,
                                              float* __restrict__ ob){
    __shared__ float Ks[64][HD+1];
    __shared__ float Vs[64][HD+1];
    __shared__ float Qs[4][HD+1];
    __shared__ float Ps[4][64];
    int blk = blockIdx.x;
    int qt = blk & (TT/4 - 1);      // 512 q-tiles per (b,h)
    int h  = (blk >> 9) & (NH-1);
    int b  = blk >> 13;
    int tid = threadIdx.x;
    int w = tid >> 6, lane = tid & 63;
    int q_row = qt*4 + w;

    Qs[w][lane] = qb[((size_t)(b*TT + q_row))*DIM + h*HD + lane];

    float m = -1e30f, l = 0.f, acc = 0.f;
    int ntiles = (qt*4)/64 + 1;     // all 4 rows share the same last tile
    for(int kt=0; kt<ntiles; kt++){
        // stage K,V tiles (also covers Qs visibility on first iter)
        #pragma unroll
        for(int rrep=0; rrep<16; rrep++){
            int j = rrep*4 + w;
            size_t g = ((size_t)(b*TT + kt*64 + j))*DIM + h*HD + lane;
            Ks[j][lane] = kb[g];
            Vs[j][lane] = vb[g];
        }
        __syncthreads();
        // scores: lane = key index within tile
        int jg = kt*64 + lane;
        float sc = -1e30f;
        if (jg <= q_row){
            float d = 0.f;
            #pragma unroll
            for(int dd=0; dd<HD; dd++) d += Qs[w][dd]*Ks[lane][dd];
            sc = d*0.125f;          // 1/sqrt(64)
        }
        float mt = wave_max(sc);
        float mn = fmaxf(m, mt);
        float alpha = expf(m - mn);
        float pv = expf(sc - mn);   // masked lanes: exp(-1e30) = 0
        float psum = wave_sum(pv);
        l = l*alpha + psum;
        m = mn;
        Ps[w][lane] = pv;
        __syncthreads();
        // PV: lane = head dim
        float a2 = 0.f;
        #pragma unroll
        for(int j=0;j<64;j++) a2 += Ps[w][j]*Vs[j][lane];
        acc = acc*alpha + a2;
        __syncthreads();            // protect Ks/Vs/Ps before next stage
    }
    ob[((size_t)(b*TT + q_row))*DIM + h*HD + lane] = acc / l;
}

// ---------------- launch ----------------
extern "C" void kernel_launch(void* const* d_in, const int* in_sizes, int n_in,
                              void* d_out, int out_size, void* d_ws, size_t ws_size,
                              hipStream_t stream){
    const float* x    = (const float*)d_in[0];
    const float* cosb = (const float*)d_in[1];
    const float* sinb = (const float*)d_in[2];
    const float* wq_w = (const float*)d_in[3];
    const float* wk_w = (const float*)d_in[4];
    const float* wv_w = (const float*)d_in[5];
    const float* wo_w = (const float*)d_in[6];
    float* out = (float*)d_out;

    float* f = (float*)d_ws;
    size_t off = 0;
    float* wqd_q = f + off; off += (size_t)DIM*DIM;
    float* wqd_k = f + off; off += (size_t)DIM*DIM;
    float* wqd_v = f + off; off += (size_t)DIM*DIM;
    float* wqd_o = f + off; off += (size_t)DIM*DIM;
    float* xq    = f + off; off += (size_t)MROWS*DIM;
    float* qb    = f + off; off += (size_t)MROWS*DIM;
    float* kb    = f + off; off += (size_t)MROWS*DIM;
    float* vb    = f + off; off += (size_t)MROWS*DIM;
    float* ao  = xq;   // attention output reuses xq (dead after QKV GEMMs)
    float* xq2 = qb;   // quantized attn-out reuses qb (dead after attention)
    // total ws use: (4 + 4*4) M floats = 80 MB

    // 1. quantize all 4 weight matrices
    quant_w<<<32, 256, 0, stream>>>(wq_w, wqd_q);
    quant_w<<<32, 256, 0, stream>>>(wk_w, wqd_k);
    quant_w<<<32, 256, 0, stream>>>(wv_w, wqd_v);
    quant_w<<<32, 256, 0, stream>>>(wo_w, wqd_o);
    // 2. quantize activations
    quant_x<<<MROWS, 256, 0, stream>>>(x, xq);
    // 3. q/k/v projections
    dim3 gg(DIM/BN, MROWS/BM);
    gemm_f32<<<gg, 256, 0, stream>>>(xq, wqd_q, qb, MROWS, DIM, DIM);
    gemm_f32<<<gg, 256, 0, stream>>>(xq, wqd_k, kb, MROWS, DIM, DIM);
    gemm_f32<<<gg, 256, 0, stream>>>(xq, wqd_v, vb, MROWS, DIM, DIM);
    // 4. RoPE on q,k
    rope_k<<<(MROWS*(DIM/2))/256, 256, 0, stream>>>(qb, kb, cosb, sinb);
    // 5. attention
    attn_k<<<BB*NH*(TT/4), 256, 0, stream>>>(qb, kb, vb, ao);
    // 6. quantize attention output
    quant_x<<<MROWS, 256, 0, stream>>>(ao, xq2);
    // 7. output projection
    gemm_f32<<<gg, 256, 0, stream>>>(xq2, wqd_o, out, MROWS, DIM, DIM);
}

// Round 2
// 774.671 us; speedup vs baseline: 2.4954x; 2.4954x over previous
//
#include <hip/hip_runtime.h>
#include <math.h>

#define DIM   1024
#define NH    16
#define HD    64
#define GRP   128
#define BB    2
#define TT    2048
#define MROWS (BB*TT)   // 4096

typedef __attribute__((ext_vector_type(8))) short s16x8;
typedef __attribute__((ext_vector_type(4))) float f32x4;

__device__ inline float wave_max(float v){
    for(int off=32; off; off>>=1) v = fmaxf(v, __shfl_xor(v, off));
    return v;
}

__device__ inline unsigned short f2bf(float x){
    union { float f; unsigned u; } v; v.f = x;
    unsigned r = v.u + 0x7fffu + ((v.u >> 16) & 1u);
    return (unsigned short)(r >> 16);
}

// ---------------- weight quantization (unchanged, verified) ----------------
__global__ void quant_w(const float* __restrict__ w, float* __restrict__ wq){
    int gidx = blockIdx.x*blockDim.x + threadIdx.x;
    if (gidx >= DIM*(DIM/GRP)) return;
    const float* p = w + (size_t)gidx*GRP;
    float r[8];
    #pragma unroll
    for(int j=0;j<8;j++) r[j] = fabsf(p[j]);
    for(int i=8;i<GRP;i+=8){
        #pragma unroll
        for(int j=0;j<8;j++) r[j] += fabsf(p[i+j]);
    }
    float s = ((r[0]+r[1])+(r[2]+r[3]))+((r[4]+r[5])+(r[6]+r[7]));
    float ws = s/(float)GRP + 1e-5f;
    float* q = wq + (size_t)gidx*GRP;
    for(int i=0;i<GRP;i++){
        float t = rintf(p[i]/ws);
        t = fminf(fmaxf(t,-1.f),1.f);
        q[i] = t*ws;
    }
}

// ---------------- activation quantization (unchanged, verified) ----------------
__global__ __launch_bounds__(256) void quant_x(const float* __restrict__ x, float* __restrict__ xq){
    int row = blockIdx.x;
    const float* p = x + (size_t)row*DIM;
    float*       q = xq + (size_t)row*DIM;
    int tid = threadIdx.x;
    float v[4];
    float m = 0.f;
    #pragma unroll
    for(int i=0;i<4;i++){ v[i] = p[tid + 256*i]; m = fmaxf(m, fabsf(v[i])); }
    m = wave_max(m);
    __shared__ float red[4];
    if ((tid&63)==0) red[tid>>6] = m;
    __syncthreads();
    m = fmaxf(fmaxf(red[0],red[1]), fmaxf(red[2],red[3]));
    float s = 127.f/(m+1e-5f);
    #pragma unroll
    for(int i=0;i<4;i++){
        float t = rintf(v[i]*s);
        t = fminf(fmaxf(t,-128.f),127.f);
        q[tid + 256*i] = t/s;
    }
}

// ---------------- fp32 GEMM (unchanged, verified) ----------------
#define BM 64
#define BN 64
#define BK 16
__global__ __launch_bounds__(256) void gemm_f32(const float* __restrict__ A,
                                                const float* __restrict__ W,
                                                float* __restrict__ C,
                                                int M, int N, int K){
    __shared__ float As[BK][BM+4];
    __shared__ float Bs[BK][BN+4];
    int tid = threadIdx.x;
    int m0 = blockIdx.y*BM, n0 = blockIdx.x*BN;
    int tx = tid & 15, ty = tid >> 4;
    int lk = tid & 15;
    int lr = tid >> 4;
    float acc[4][4] = {};
    for(int k0=0;k0<K;k0+=BK){
        #pragma unroll
        for(int i=0;i<4;i++){
            As[lk][lr+16*i] = A[(size_t)(m0+lr+16*i)*K + k0+lk];
            Bs[lk][lr+16*i] = W[(size_t)(n0+lr+16*i)*K + k0+lk];
        }
        __syncthreads();
        #pragma unroll
        for(int kk=0;kk<BK;kk++){
            float a[4],b[4];
            #pragma unroll
            for(int i=0;i<4;i++) a[i]=As[kk][ty*4+i];
            #pragma unroll
            for(int j=0;j<4;j++) b[j]=Bs[kk][tx*4+j];
            #pragma unroll
            for(int i=0;i<4;i++)
                #pragma unroll
                for(int j=0;j<4;j++) acc[i][j] += a[i]*b[j];
        }
        __syncthreads();
    }
    #pragma unroll
    for(int i=0;i<4;i++)
        #pragma unroll
        for(int j=0;j<4;j++)
            C[(size_t)(m0+ty*4+i)*N + n0+tx*4+j] = acc[i][j];
}

// ---------------- pack Q,K: rope + fp32->bf16 + head-major [b,h,t,d] ----------------
__global__ __launch_bounds__(256) void pack_qk(const float* __restrict__ qb,
                                               const float* __restrict__ kb,
                                               const float* __restrict__ cosb,
                                               const float* __restrict__ sinb,
                                               unsigned short* __restrict__ Qh,
                                               unsigned short* __restrict__ Kh){
    int idx = blockIdx.x*blockDim.x + threadIdx.x;  // MROWS*512 pairs
    int bt = idx >> 9;
    int r  = idx & 511;
    int h  = r >> 5;
    int p  = r & 31;
    int b  = bt >> 11;
    int t  = bt & (TT-1);
    float c = cosb[t*32+p], s = sinb[t*32+p];
    size_t src = (size_t)bt*DIM + h*HD + 2*p;
    size_t dst = ((size_t)(b*NH + h)*TT + t)*HD + 2*p;
    float q0 = qb[src], q1 = qb[src+1];
    float k0 = kb[src], k1 = kb[src+1];
    float qe = q0*c - q1*s, qo = q0*s + q1*c;
    float ke = k0*c - k1*s, ko = k0*s + k1*c;
    *(ushort2*)(Qh + dst) = make_ushort2(f2bf(qe), f2bf(qo));
    *(ushort2*)(Kh + dst) = make_ushort2(f2bf(ke), f2bf(ko));
}

// ---------------- pack V: fp32 [b,t,h,d] -> bf16 transposed [b,h,d,t] ----------------
__global__ __launch_bounds__(256) void pack_v(const float* __restrict__ vb,
                                              unsigned short* __restrict__ Vt){
    __shared__ float st[64][65];
    int blk = blockIdx.x;
    int t0 = (blk & 31)*64;
    int h  = (blk >> 5) & (NH-1);
    int b  = blk >> 9;
    int tid = threadIdx.x;
    #pragma unroll
    for(int rep=0; rep<16; rep++){
        int idx = rep*256 + tid;
        int i = idx >> 6, d = idx & 63;
        st[i][d] = vb[(size_t)(b*TT + t0 + i)*DIM + h*HD + d];
    }
    __syncthreads();
    size_t base = ((size_t)(b*NH + h)*HD)*TT;
    #pragma unroll
    for(int rep=0; rep<8; rep++){
        int idx = rep*256 + tid;
        int d  = idx >> 5;
        int tp = (idx & 31)*2;
        *(ushort2*)(Vt + base + (size_t)d*TT + t0 + tp) =
            make_ushort2(f2bf(st[tp][d]), f2bf(st[tp+1][d]));
    }
}

// ---------------- MFMA flash attention ----------------
// Workgroup: 4 waves = 64 q rows. Computes S^T = K*Q^T so softmax state is
// lane-uniform (col=q=lane&15). K/V tiles staged in LDS in FRAGMENT ORDER:
// frag (f,c) at [(f*2+c)*64 + lane] -> stride-1 ds_read_b128, conflict-free.
__global__ __launch_bounds__(256) void attn_mfma(const unsigned short* __restrict__ Qh,
                                                 const unsigned short* __restrict__ Kh,
                                                 const unsigned short* __restrict__ Vt,
                                                 float* __restrict__ ao){
    __shared__ s16x8 Kfr[512];   // 8 KB
    __shared__ s16x8 Vfr[512];   // 8 KB
    int blk = blockIdx.x;
    int qb_ = 31 - (blk & 31);          // heavy blocks first
    int h   = (blk >> 5) & (NH-1);
    int b   = blk >> 9;
    int bh  = b*NH + h;
    const unsigned short* Qhead = Qh + (size_t)bh*TT*HD;
    const unsigned short* Khead = Kh + (size_t)bh*TT*HD;
    const unsigned short* Vhead = Vt + (size_t)bh*HD*TT;

    int tid = threadIdx.x;
    int w = tid >> 6, lane = tid & 63;
    int m = lane & 15, g = lane >> 4;
    int qg0 = qb_*64 + w*16;
    int q   = qg0 + m;                  // this lane's q column

    // Q fragments (B operand): lane holds q=lane&15, dims g*8+j (+32 for chunk 1)
    s16x8 Qf0 = *(const s16x8*)(Qhead + (size_t)q*HD + g*8);
    s16x8 Qf1 = *(const s16x8*)(Qhead + (size_t)q*HD + g*8 + 32);

    f32x4 Of[4] = {f32x4{0,0,0,0}, f32x4{0,0,0,0}, f32x4{0,0,0,0}, f32x4{0,0,0,0}};
    float mrow = -1e30f, lrow = 0.f;

    int ntiles = qb_ + 1;
    for(int kt=0; kt<ntiles; kt++){
        // ---- stage K,V tiles in fragment order ----
        const unsigned short* Kt = Khead + (size_t)kt*64*HD;
        #pragma unroll
        for(int rep=0; rep<2; rep++){
            int W = rep*256 + tid;
            int f = W >> 7, c = (W >> 6) & 1, mm = W & 15, gg = (W >> 4) & 3;
            int row = 16*f + mm;
            int d0  = 8*gg + 32*c;
            Kfr[W] = *(const s16x8*)(Kt + (size_t)row*HD + d0);
            Vfr[W] = *(const s16x8*)(Vhead + (size_t)row*TT + kt*64 + d0);
        }
        __syncthreads();

        // ---- S^T = K * Q^T : 4 key tiles of 16 ----
        f32x4 S[4];
        #pragma unroll
        for(int f=0; f<4; f++){
            s16x8 k0 = Kfr[(f*2+0)*64 + lane];
            s16x8 k1 = Kfr[(f*2+1)*64 + lane];
            f32x4 acc = {0,0,0,0};
            acc = __builtin_amdgcn_mfma_f32_16x16x32_bf16(k0, Qf0, acc, 0, 0, 0);
            acc = __builtin_amdgcn_mfma_f32_16x16x32_bf16(k1, Qf1, acc, 0, 0, 0);
            S[f] = acc;
        }

        // ---- online softmax (per-lane q, keys spread over f,r and g-groups) ----
        bool diag = (kt == qb_);
        float p[4][4];
        float mloc = -1e30f;
        #pragma unroll
        for(int f=0; f<4; f++)
            #pragma unroll
            for(int r=0; r<4; r++){
                float s = S[f][r]*0.125f;
                if (diag){
                    int key = kt*64 + 16*f + 4*g + r;
                    if (key > q) s = -1e30f;
                }
                p[f][r] = s;
                mloc = fmaxf(mloc, s);
            }
        mloc = fmaxf(mloc, __shfl_xor(mloc, 16));
        mloc = fmaxf(mloc, __shfl_xor(mloc, 32));
        float mn = fmaxf(mrow, mloc);
        float alpha = __expf(mrow - mn);
        float ps = 0.f;
        #pragma unroll
        for(int f=0; f<4; f++)
            #pragma unroll
            for(int r=0; r<4; r++){
                float e = __expf(p[f][r] - mn);
                p[f][r] = e;
                ps += e;
            }
        ps += __shfl_xor(ps, 16);
        ps += __shfl_xor(ps, 32);
        lrow = lrow*alpha + ps;
        mrow = mn;

        // rescale accumulator (alpha is lane-uniform scalar)
        #pragma unroll
        for(int f2=0; f2<4; f2++)
            #pragma unroll
            for(int r=0; r<4; r++) Of[f2][r] *= alpha;

        // pack P rows to bf16 pairs: pp[0][f]=(r0,r1), pp[1][f]=(r2,r3)
        unsigned pp0[4], pp1[4];
        #pragma unroll
        for(int f=0; f<4; f++){
            pp0[f] = (unsigned)f2bf(p[f][0]) | ((unsigned)f2bf(p[f][1]) << 16);
            pp1[f] = (unsigned)f2bf(p[f][2]) | ((unsigned)f2bf(p[f][3]) << 16);
        }

        // ---- PV: O^T += V^T * P^T ----
        // B-frag (n=q, k=key): lane needs keys 32c+8g+j from source lanes
        // src = m + 16*(2*(g&1)) (+16), register f_s = 2c + (g>>1).
        int src0 = m + 16*(2*(g&1));
        int src1 = src0 + 16;
        bool hi = (g >= 2);
        #pragma unroll
        for(int c=0; c<2; c++){
            unsigned a0 = (unsigned)__shfl((int)pp0[2*c],   src0);
            unsigned a1 = (unsigned)__shfl((int)pp0[2*c+1], src0);
            unsigned b0 = hi ? a1 : a0;
            unsigned a2 = (unsigned)__shfl((int)pp1[2*c],   src0);
            unsigned a3 = (unsigned)__shfl((int)pp1[2*c+1], src0);
            unsigned b1 = hi ? a3 : a2;
            unsigned a4 = (unsigned)__shfl((int)pp0[2*c],   src1);
            unsigned a5 = (unsigned)__shfl((int)pp0[2*c+1], src1);
            unsigned b2 = hi ? a5 : a4;
            unsigned a6 = (unsigned)__shfl((int)pp1[2*c],   src1);
            unsigned a7 = (unsigned)__shfl((int)pp1[2*c+1], src1);
            unsigned b3 = hi ? a7 : a6;
            union { unsigned u[4]; s16x8 v; } Bf;
            Bf.u[0]=b0; Bf.u[1]=b1; Bf.u[2]=b2; Bf.u[3]=b3;
            #pragma unroll
            for(int f2=0; f2<4; f2++){
                s16x8 vf = Vfr[(f2*2+c)*64 + lane];
                Of[f2] = __builtin_amdgcn_mfma_f32_16x16x32_bf16(vf, Bf.v, Of[f2], 0, 0, 0);
            }
        }
        __syncthreads();   // protect Kfr/Vfr before next stage
    }

    // ---- epilogue: O^T[dim][q] -> ao[b,t,h*64+dim] ----
    float invl = 1.0f / lrow;
    size_t obase = (size_t)(b*TT + q)*DIM + h*HD;
    #pragma unroll
    for(int f2=0; f2<4; f2++)
        #pragma unroll
        for(int r=0; r<4; r++)
            ao[obase + 16*f2 + 4*g + r] = Of[f2][r]*invl;
}

// ---------------- launch ----------------
extern "C" void kernel_launch(void* const* d_in, const int* in_sizes, int n_in,
                              void* d_out, int out_size, void* d_ws, size_t ws_size,
                              hipStream_t stream){
    const float* x    = (const float*)d_in[0];
    const float* cosb = (const float*)d_in[1];
    const float* sinb = (const float*)d_in[2];
    const float* wq_w = (const float*)d_in[3];
    const float* wk_w = (const float*)d_in[4];
    const float* wv_w = (const float*)d_in[5];
    const float* wo_w = (const float*)d_in[6];
    float* out = (float*)d_out;

    float* f = (float*)d_ws;
    const size_t M1 = 1048576;
    // regions (floats): [0,4M) wqd x4 | [4M,8M) A | [8M,12M) B | [12M,16M) C | [16M,20M) D
    float* wqd_q = f;
    float* wqd_k = f + 1*M1;
    float* wqd_v = f + 2*M1;
    float* wqd_o = f + 3*M1;
    float* xq    = f + 4*M1;                       // region A (fp32 phase)
    float* qb    = f + 8*M1;                       // region B
    float* kb    = f + 12*M1;                      // region C
    float* vb    = f + 16*M1;                      // region D
    unsigned short* Qh = (unsigned short*)(f + 4*M1);   // A lower half (xq dead)
    unsigned short* Kh = (unsigned short*)(f + 6*M1);   // A upper half
    unsigned short* Vt = (unsigned short*)(f + 8*M1);   // B lower half (qb dead)
    float* ao  = f + 12*M1;                        // region C (kb dead)
    float* xq2 = f + 16*M1;                        // region D (vb dead)

    quant_w<<<32, 256, 0, stream>>>(wq_w, wqd_q);
    quant_w<<<32, 256, 0, stream>>>(wk_w, wqd_k);
    quant_w<<<32, 256, 0, stream>>>(wv_w, wqd_v);
    quant_w<<<32, 256, 0, stream>>>(wo_w, wqd_o);
    quant_x<<<MROWS, 256, 0, stream>>>(x, xq);

    dim3 gg(DIM/BN, MROWS/BM);
    gemm_f32<<<gg, 256, 0, stream>>>(xq, wqd_q, qb, MROWS, DIM, DIM);
    gemm_f32<<<gg, 256, 0, stream>>>(xq, wqd_k, kb, MROWS, DIM, DIM);
    gemm_f32<<<gg, 256, 0, stream>>>(xq, wqd_v, vb, MROWS, DIM, DIM);

    pack_qk<<<(MROWS*512)/256, 256, 0, stream>>>(qb, kb, cosb, sinb, Qh, Kh);
    pack_v<<<BB*NH*(TT/64), 256, 0, stream>>>(vb, Vt);

    attn_mfma<<<BB*NH*(TT/64), 256, 0, stream>>>(Qh, Kh, Vt, ao);

    quant_x<<<MROWS, 256, 0, stream>>>(ao, xq2);
    gemm_f32<<<gg, 256, 0, stream>>>(xq2, wqd_o, out, MROWS, DIM, DIM);
}

// Round 3
// 364.407 us; speedup vs baseline: 5.3049x; 2.1258x over previous
//
#include <hip/hip_runtime.h>
#include <math.h>

#define DIM   1024
#define NH    16
#define HD    64
#define GRP   128
#define BB    2
#define TT    2048
#define MROWS (BB*TT)   // 4096

typedef __attribute__((ext_vector_type(8))) short s16x8;
typedef __attribute__((ext_vector_type(4))) float f32x4;
typedef __attribute__((ext_vector_type(4))) int   i32x4;
typedef __attribute__((ext_vector_type(16))) int  i32x16;

__device__ inline float wave_max(float v){
    for(int off=32; off; off>>=1) v = fmaxf(v, __shfl_xor(v, off));
    return v;
}

__device__ inline unsigned short f2bf(float x){
    union { float f; unsigned u; } v; v.f = x;
    unsigned r = v.u + 0x7fffu + ((v.u >> 16) & 1u);
    return (unsigned short)(r >> 16);
}

__device__ inline i32x16 zero16(){
    i32x16 z;
    #pragma unroll
    for(int i=0;i<16;i++) z[i]=0;
    return z;
}

__device__ inline void gload16(const void* g, void* l){
    __builtin_amdgcn_global_load_lds((const __attribute__((address_space(1))) unsigned int*)g,
                                     (__attribute__((address_space(3))) unsigned int*)l, 16, 0, 0);
}

// ---------------- weight quantization -> ternary int8 + per-group scale ----------------
__global__ void quant_w_i8(const float* __restrict__ w, char* __restrict__ w8,
                           float* __restrict__ wsout){
    int gidx = blockIdx.x*blockDim.x + threadIdx.x;   // 8192 groups (n*8+g)
    if (gidx >= DIM*(DIM/GRP)) return;
    const float* p = w + (size_t)gidx*GRP;
    float r[8];
    #pragma unroll
    for(int j=0;j<8;j++) r[j] = fabsf(p[j]);
    for(int i=8;i<GRP;i+=8){
        #pragma unroll
        for(int j=0;j<8;j++) r[j] += fabsf(p[i+j]);
    }
    float s = ((r[0]+r[1])+(r[2]+r[3]))+((r[4]+r[5])+(r[6]+r[7]));
    float ws = s/(float)GRP + 1e-5f;
    wsout[gidx] = ws;
    int* q = (int*)(w8 + (size_t)gidx*GRP);
    for(int i=0;i<GRP;i+=4){
        int pk = 0;
        #pragma unroll
        for(int j=0;j<4;j++){
            float t = rintf(p[i+j]/ws);
            t = fminf(fmaxf(t,-1.f),1.f);
            pk |= ((int)t & 0xff) << (8*j);
        }
        q[i>>2] = pk;
    }
}

// ---------------- activation quantization -> int8 + per-row scale ----------------
__global__ __launch_bounds__(256) void quant_x_i8(const float* __restrict__ x,
                                                  char* __restrict__ xq8,
                                                  float* __restrict__ srow){
    int row = blockIdx.x;
    int tid = threadIdx.x;
    const float* p = x + (size_t)row*DIM;
    float4 v = *(const float4*)(p + tid*4);
    float m = fmaxf(fmaxf(fabsf(v.x),fabsf(v.y)), fmaxf(fabsf(v.z),fabsf(v.w)));
    m = wave_max(m);
    __shared__ float red[4];
    if ((tid&63)==0) red[tid>>6] = m;
    __syncthreads();
    m = fmaxf(fmaxf(red[0],red[1]), fmaxf(red[2],red[3]));
    float s = 127.f/(m+1e-5f);
    int a0 = (int)fminf(fmaxf(rintf(v.x*s),-128.f),127.f);
    int a1 = (int)fminf(fmaxf(rintf(v.y*s),-128.f),127.f);
    int a2 = (int)fminf(fmaxf(rintf(v.z*s),-128.f),127.f);
    int a3 = (int)fminf(fmaxf(rintf(v.w*s),-128.f),127.f);
    int pk = (a0&0xff) | ((a1&0xff)<<8) | ((a2&0xff)<<16) | ((a3&0xff)<<24);
    ((int*)xq8)[(size_t)row*256 + tid] = pk;
    if (tid==0) srow[row] = s;
}

// ---------------- int8 MFMA GEMM ----------------
// C[M,1024] = dequant( A8[M,1024] . W8[1024,1024]^T )
// block 128x128, BK=128 (= one quant group), 4 waves in 2x2, wave = 2x2 of 32x32.
// LDS staged via global_load_lds(16B) with XOR-row swizzle: global reads stay
// 128B-coalesced (swizzle permutes within a row), ds_read_b128 frag reads are
// spread over all 32 banks.
__global__ __launch_bounds__(256) void gemm_i8(const char* __restrict__ A8,
                                               const char* __restrict__ W8,
                                               const float* __restrict__ wsb,
                                               const float* __restrict__ srow,
                                               float* __restrict__ C){
    __shared__ __align__(16) char As[16384];
    __shared__ __align__(16) char Bs[16384];
    int tid = threadIdx.x;
    int w = tid >> 6, lane = tid & 63;
    int wm = w >> 1, wn = w & 1;
    int m0 = blockIdx.y*128, n0 = blockIdx.x*128;
    int l31 = lane & 31, lh = lane >> 5;

    // per-group weight scales for this lane's two output columns
    float wsr[2][8];
    #pragma unroll
    for(int jt=0; jt<2; jt++){
        int col = n0 + wn*64 + jt*32 + l31;
        float4 w0 = *(const float4*)(wsb + (size_t)col*8);
        float4 w1 = *(const float4*)(wsb + (size_t)col*8 + 4);
        wsr[jt][0]=w0.x; wsr[jt][1]=w0.y; wsr[jt][2]=w0.z; wsr[jt][3]=w0.w;
        wsr[jt][4]=w1.x; wsr[jt][5]=w1.y; wsr[jt][6]=w1.z; wsr[jt][7]=w1.w;
    }

    float facc[2][2][16];
    #pragma unroll
    for(int a=0;a<2;a++)
        #pragma unroll
        for(int b=0;b<2;b++)
            #pragma unroll
            for(int r=0;r<16;r++) facc[a][b][r]=0.f;

    int srow8 = lane >> 3;          // staging: row sub-index
    int scol  = (lane&7) ^ ((lane>>3)&7);  // staging: swizzled 16B chunk

    #pragma unroll
    for(int g=0; g<8; g++){
        // ---- stage A (waves 0,1) and B (waves 2,3): 8 x 1KB wave-insts each ----
        const char* Ablk = A8 + (size_t)m0*1024 + g*128;
        const char* Bblk = W8 + (size_t)n0*1024 + g*128;
        if (w < 2){
            #pragma unroll
            for(int r=0;r<8;r++){
                int Wi = w*8 + r;
                gload16(Ablk + (size_t)(Wi*8 + srow8)*1024 + scol*16, As + Wi*1024);
            }
        } else {
            #pragma unroll
            for(int r=0;r<8;r++){
                int Wi = (w-2)*8 + r;
                gload16(Bblk + (size_t)(Wi*8 + srow8)*1024 + scol*16, Bs + Wi*1024);
            }
        }
        __syncthreads();

        // ---- 4 k-steps of 32 over this group ----
        i32x16 iacc[2][2];
        iacc[0][0]=zero16(); iacc[0][1]=zero16();
        iacc[1][0]=zero16(); iacc[1][1]=zero16();
        #pragma unroll
        for(int s=0; s<4; s++){
            int cw = s*2 + lh;
            i32x4 af[2], bf[2];
            #pragma unroll
            for(int it=0; it<2; it++){
                int rl = wm*64 + it*32 + l31;
                int entry = rl*8 + (cw ^ (rl&7));
                af[it] = *(const i32x4*)(As + entry*16);
            }
            #pragma unroll
            for(int jt=0; jt<2; jt++){
                int rl = wn*64 + jt*32 + l31;
                int entry = rl*8 + (cw ^ (rl&7));
                bf[jt] = *(const i32x4*)(Bs + entry*16);
            }
            #pragma unroll
            for(int it=0; it<2; it++)
                #pragma unroll
                for(int jt=0; jt<2; jt++)
                    iacc[it][jt] = __builtin_amdgcn_mfma_i32_32x32x32_i8(af[it], bf[jt], iacc[it][jt], 0, 0, 0);
        }
        // ---- apply this group's weight scale ----
        #pragma unroll
        for(int it=0; it<2; it++)
            #pragma unroll
            for(int jt=0; jt<2; jt++)
                #pragma unroll
                for(int r=0;r<16;r++)
                    facc[it][jt][r] += (float)iacc[it][jt][r] * wsr[jt][g];
        __syncthreads();
    }

    // ---- epilogue: divide by per-token scale, store fp32 ----
    #pragma unroll
    for(int it=0; it<2; it++){
        #pragma unroll
        for(int r=0; r<16; r++){
            int rowl = wm*64 + it*32 + (r&3) + 8*(r>>2) + 4*lh;
            float sv = srow[m0 + rowl];
            #pragma unroll
            for(int jt=0; jt<2; jt++){
                int col = n0 + wn*64 + jt*32 + l31;
                C[(size_t)(m0+rowl)*DIM + col] = facc[it][jt][r] / sv;
            }
        }
    }
}

// ---------------- pack Q,K: rope + fp32->bf16 + head-major [b,h,t,d] ----------------
__global__ __launch_bounds__(256) void pack_qk(const float* __restrict__ qb,
                                               const float* __restrict__ kb,
                                               const float* __restrict__ cosb,
                                               const float* __restrict__ sinb,
                                               unsigned short* __restrict__ Qh,
                                               unsigned short* __restrict__ Kh){
    int idx = blockIdx.x*blockDim.x + threadIdx.x;  // MROWS*512 pairs
    int bt = idx >> 9;
    int r  = idx & 511;
    int h  = r >> 5;
    int p  = r & 31;
    int b  = bt >> 11;
    int t  = bt & (TT-1);
    float c = cosb[t*32+p], s = sinb[t*32+p];
    size_t src = (size_t)bt*DIM + h*HD + 2*p;
    size_t dst = ((size_t)(b*NH + h)*TT + t)*HD + 2*p;
    float q0 = qb[src], q1 = qb[src+1];
    float k0 = kb[src], k1 = kb[src+1];
    float qe = q0*c - q1*s, qo = q0*s + q1*c;
    float ke = k0*c - k1*s, ko = k0*s + k1*c;
    *(ushort2*)(Qh + dst) = make_ushort2(f2bf(qe), f2bf(qo));
    *(ushort2*)(Kh + dst) = make_ushort2(f2bf(ke), f2bf(ko));
}

// ---------------- pack V: fp32 [b,t,h,d] -> bf16 transposed [b,h,d,t] ----------------
__global__ __launch_bounds__(256) void pack_v(const float* __restrict__ vb,
                                              unsigned short* __restrict__ Vt){
    __shared__ float st[64][65];
    int blk = blockIdx.x;
    int t0 = (blk & 31)*64;
    int h  = (blk >> 5) & (NH-1);
    int b  = blk >> 9;
    int tid = threadIdx.x;
    #pragma unroll
    for(int rep=0; rep<16; rep++){
        int idx = rep*256 + tid;
        int i = idx >> 6, d = idx & 63;
        st[i][d] = vb[(size_t)(b*TT + t0 + i)*DIM + h*HD + d];
    }
    __syncthreads();
    size_t base = ((size_t)(b*NH + h)*HD)*TT;
    #pragma unroll
    for(int rep=0; rep<8; rep++){
        int idx = rep*256 + tid;
        int d  = idx >> 5;
        int tp = (idx & 31)*2;
        *(ushort2*)(Vt + base + (size_t)d*TT + t0 + tp) =
            make_ushort2(f2bf(st[tp][d]), f2bf(st[tp+1][d]));
    }
}

// ---------------- MFMA flash attention (verified round 2) ----------------
__global__ __launch_bounds__(256) void attn_mfma(const unsigned short* __restrict__ Qh,
                                                 const unsigned short* __restrict__ Kh,
                                                 const unsigned short* __restrict__ Vt,
                                                 float* __restrict__ ao){
    __shared__ s16x8 Kfr[512];
    __shared__ s16x8 Vfr[512];
    int blk = blockIdx.x;
    int qb_ = 31 - (blk & 31);          // heavy blocks first
    int h   = (blk >> 5) & (NH-1);
    int b   = blk >> 9;
    int bh  = b*NH + h;
    const unsigned short* Qhead = Qh + (size_t)bh*TT*HD;
    const unsigned short* Khead = Kh + (size_t)bh*TT*HD;
    const unsigned short* Vhead = Vt + (size_t)bh*HD*TT;

    int tid = threadIdx.x;
    int w = tid >> 6, lane = tid & 63;
    int m = lane & 15, g = lane >> 4;
    int qg0 = qb_*64 + w*16;
    int q   = qg0 + m;

    s16x8 Qf0 = *(const s16x8*)(Qhead + (size_t)q*HD + g*8);
    s16x8 Qf1 = *(const s16x8*)(Qhead + (size_t)q*HD + g*8 + 32);

    f32x4 Of[4] = {f32x4{0,0,0,0}, f32x4{0,0,0,0}, f32x4{0,0,0,0}, f32x4{0,0,0,0}};
    float mrow = -1e30f, lrow = 0.f;

    int ntiles = qb_ + 1;
    for(int kt=0; kt<ntiles; kt++){
        const unsigned short* Kt = Khead + (size_t)kt*64*HD;
        #pragma unroll
        for(int rep=0; rep<2; rep++){
            int W = rep*256 + tid;
            int f = W >> 7, c = (W >> 6) & 1, mm = W & 15, gg = (W >> 4) & 3;
            int row = 16*f + mm;
            int d0  = 8*gg + 32*c;
            Kfr[W] = *(const s16x8*)(Kt + (size_t)row*HD + d0);
            Vfr[W] = *(const s16x8*)(Vhead + (size_t)row*TT + kt*64 + d0);
        }
        __syncthreads();

        f32x4 S[4];
        #pragma unroll
        for(int f=0; f<4; f++){
            s16x8 k0 = Kfr[(f*2+0)*64 + lane];
            s16x8 k1 = Kfr[(f*2+1)*64 + lane];
            f32x4 acc = {0,0,0,0};
            acc = __builtin_amdgcn_mfma_f32_16x16x32_bf16(k0, Qf0, acc, 0, 0, 0);
            acc = __builtin_amdgcn_mfma_f32_16x16x32_bf16(k1, Qf1, acc, 0, 0, 0);
            S[f] = acc;
        }

        bool diag = (kt == qb_);
        float p[4][4];
        float mloc = -1e30f;
        #pragma unroll
        for(int f=0; f<4; f++)
            #pragma unroll
            for(int r=0; r<4; r++){
                float s = S[f][r]*0.125f;
                if (diag){
                    int key = kt*64 + 16*f + 4*g + r;
                    if (key > q) s = -1e30f;
                }
                p[f][r] = s;
                mloc = fmaxf(mloc, s);
            }
        mloc = fmaxf(mloc, __shfl_xor(mloc, 16));
        mloc = fmaxf(mloc, __shfl_xor(mloc, 32));
        float mn = fmaxf(mrow, mloc);
        float alpha = __expf(mrow - mn);
        float ps = 0.f;
        #pragma unroll
        for(int f=0; f<4; f++)
            #pragma unroll
            for(int r=0; r<4; r++){
                float e = __expf(p[f][r] - mn);
                p[f][r] = e;
                ps += e;
            }
        ps += __shfl_xor(ps, 16);
        ps += __shfl_xor(ps, 32);
        lrow = lrow*alpha + ps;
        mrow = mn;

        #pragma unroll
        for(int f2=0; f2<4; f2++)
            #pragma unroll
            for(int r=0; r<4; r++) Of[f2][r] *= alpha;

        unsigned pp0[4], pp1[4];
        #pragma unroll
        for(int f=0; f<4; f++){
            pp0[f] = (unsigned)f2bf(p[f][0]) | ((unsigned)f2bf(p[f][1]) << 16);
            pp1[f] = (unsigned)f2bf(p[f][2]) | ((unsigned)f2bf(p[f][3]) << 16);
        }

        int src0 = m + 16*(2*(g&1));
        int src1 = src0 + 16;
        bool hi = (g >= 2);
        #pragma unroll
        for(int c=0; c<2; c++){
            unsigned a0 = (unsigned)__shfl((int)pp0[2*c],   src0);
            unsigned a1 = (unsigned)__shfl((int)pp0[2*c+1], src0);
            unsigned b0 = hi ? a1 : a0;
            unsigned a2 = (unsigned)__shfl((int)pp1[2*c],   src0);
            unsigned a3 = (unsigned)__shfl((int)pp1[2*c+1], src0);
            unsigned b1 = hi ? a3 : a2;
            unsigned a4 = (unsigned)__shfl((int)pp0[2*c],   src1);
            unsigned a5 = (unsigned)__shfl((int)pp0[2*c+1], src1);
            unsigned b2 = hi ? a5 : a4;
            unsigned a6 = (unsigned)__shfl((int)pp1[2*c],   src1);
            unsigned a7 = (unsigned)__shfl((int)pp1[2*c+1], src1);
            unsigned b3 = hi ? a7 : a6;
            union { unsigned u[4]; s16x8 v; } Bf;
            Bf.u[0]=b0; Bf.u[1]=b1; Bf.u[2]=b2; Bf.u[3]=b3;
            #pragma unroll
            for(int f2=0; f2<4; f2++){
                s16x8 vf = Vfr[(f2*2+c)*64 + lane];
                Of[f2] = __builtin_amdgcn_mfma_f32_16x16x32_bf16(vf, Bf.v, Of[f2], 0, 0, 0);
            }
        }
        __syncthreads();
    }

    float invl = 1.0f / lrow;
    size_t obase = (size_t)(b*TT + q)*DIM + h*HD;
    #pragma unroll
    for(int f2=0; f2<4; f2++)
        #pragma unroll
        for(int r=0; r<4; r++)
            ao[obase + 16*f2 + 4*g + r] = Of[f2][r]*invl;
}

// ---------------- launch ----------------
extern "C" void kernel_launch(void* const* d_in, const int* in_sizes, int n_in,
                              void* d_out, int out_size, void* d_ws, size_t ws_size,
                              hipStream_t stream){
    const float* x    = (const float*)d_in[0];
    const float* cosb = (const float*)d_in[1];
    const float* sinb = (const float*)d_in[2];
    const float* wq_w = (const float*)d_in[3];
    const float* wk_w = (const float*)d_in[4];
    const float* wv_w = (const float*)d_in[5];
    const float* wo_w = (const float*)d_in[6];
    float* out = (float*)d_out;

    float* f = (float*)d_ws;
    char*  cw = (char*)d_ws;
    const size_t M4 = 262144;   // 0.25M floats = 1 MB
    // [0,1M fl): ternary weights (4 x 1MB chars)
    char* w8q = cw;
    char* w8k = cw + 1048576;
    char* w8v = cw + 2097152;
    char* w8o = cw + 3145728;
    // [1M,1.25M fl): scales
    float* wsq   = f + 4*M4;
    float* wsk   = wsq + 8192;
    float* wsv   = wsk + 8192;
    float* wso   = wsv + 8192;
    float* srow1 = wso + 8192;
    float* srow2 = srow1 + 4096;
    // int8 activations
    char* xq8   = (char*)(f + 5*M4);    // 4 MB
    char* xq8_2 = (char*)(f + 9*M4);    // 4 MB
    // fp32 intermediates
    float* qb = f + 13*M4;              // 16 MB
    float* kb = f + 29*M4;              // 16 MB
    float* vb = f + 45*M4;              // 16 MB
    unsigned short* Qh = (unsigned short*)(f + 61*M4);  // 8 MB
    unsigned short* Kh = (unsigned short*)(f + 69*M4);  // 8 MB (ends at 77*M4 = 77MB)
    unsigned short* Vt = (unsigned short*)qb;           // reuse qb after pack_qk
    float* ao = kb;                                     // reuse kb after pack_qk

    quant_w_i8<<<32, 256, 0, stream>>>(wq_w, w8q, wsq);
    quant_w_i8<<<32, 256, 0, stream>>>(wk_w, w8k, wsk);
    quant_w_i8<<<32, 256, 0, stream>>>(wv_w, w8v, wsv);
    quant_w_i8<<<32, 256, 0, stream>>>(wo_w, w8o, wso);
    quant_x_i8<<<MROWS, 256, 0, stream>>>(x, xq8, srow1);

    dim3 gg(DIM/128, MROWS/128);   // (8, 32)
    gemm_i8<<<gg, 256, 0, stream>>>(xq8, w8q, wsq, srow1, qb);
    gemm_i8<<<gg, 256, 0, stream>>>(xq8, w8k, wsk, srow1, kb);
    gemm_i8<<<gg, 256, 0, stream>>>(xq8, w8v, wsv, srow1, vb);

    pack_qk<<<(MROWS*512)/256, 256, 0, stream>>>(qb, kb, cosb, sinb, Qh, Kh);
    pack_v<<<BB*NH*(TT/64), 256, 0, stream>>>(vb, Vt);

    attn_mfma<<<BB*NH*(TT/64), 256, 0, stream>>>(Qh, Kh, Vt, ao);

    quant_x_i8<<<MROWS, 256, 0, stream>>>(ao, xq8_2, srow2);
    gemm_i8<<<gg, 256, 0, stream>>>(xq8_2, w8o, wso, srow2, out);
}

// Round 4
// 261.197 us; speedup vs baseline: 7.4011x; 1.3951x over previous
//
#include <hip/hip_runtime.h>
#include <math.h>

#define DIM   1024
#define NH    16
#define HD    64
#define GRP   128
#define BB    2
#define TT    2048
#define MROWS (BB*TT)   // 4096

typedef __attribute__((ext_vector_type(8))) short s16x8;
typedef __attribute__((ext_vector_type(4))) float f32x4;
typedef __attribute__((ext_vector_type(4))) int   i32x4;
typedef __attribute__((ext_vector_type(16))) int  i32x16;

__device__ inline float wave_max(float v){
    for(int off=32; off; off>>=1) v = fmaxf(v, __shfl_xor(v, off));
    return v;
}

__device__ inline unsigned short f2bf(float x){
    union { float f; unsigned u; } v; v.f = x;
    unsigned r = v.u + 0x7fffu + ((v.u >> 16) & 1u);
    return (unsigned short)(r >> 16);
}

__device__ inline i32x16 zero16(){
    i32x16 z;
    #pragma unroll
    for(int i=0;i<16;i++) z[i]=0;
    return z;
}

__device__ inline void gload16(const void* g, void* l){
    __builtin_amdgcn_global_load_lds((const __attribute__((address_space(1))) unsigned int*)g,
                                     (__attribute__((address_space(3))) unsigned int*)l, 16, 0, 0);
}

// ---------------- fused weight quantization: 8 lanes per group ----------------
// Lane j reproduces numpy's accumulator j (i = j, j+8, ..., sequential), then
// shfl_xor tree reproduces ((r0+r1)+(r2+r3))+((r4+r5)+(r6+r7)) exactly.
__global__ __launch_bounds__(256) void quant_w4(const float* __restrict__ w0,
                                                const float* __restrict__ w1,
                                                const float* __restrict__ w2,
                                                const float* __restrict__ w3,
                                                char* __restrict__ w8,
                                                float* __restrict__ wsall){
    int blk = blockIdx.x;             // 1024 blocks
    int widx = blk >> 8;
    const float* w = (widx==0)?w0 : (widx==1)?w1 : (widx==2)?w2 : w3;
    int tid = threadIdx.x;
    int gloc = (blk & 255)*32 + (tid >> 3);   // group 0..8191
    int j = tid & 7;
    const float* p = w + (size_t)gloc*GRP;
    float r = 0.f;
    #pragma unroll
    for(int i=0;i<16;i++) r += fabsf(p[8*i + j]);
    r += __shfl_xor(r, 1);
    r += __shfl_xor(r, 2);
    r += __shfl_xor(r, 4);
    float ws = r/(float)GRP + 1e-5f;
    if (j == 0) wsall[widx*8192 + gloc] = ws;
    int* q = (int*)(w8 + (size_t)widx*1048576 + (size_t)gloc*GRP);
    int i0 = j*16;
    #pragma unroll
    for(int c4=0;c4<4;c4++){
        float4 v = *(const float4*)(p + i0 + c4*4);
        int b0 = (int)fminf(fmaxf(rintf(v.x/ws),-1.f),1.f);
        int b1 = (int)fminf(fmaxf(rintf(v.y/ws),-1.f),1.f);
        int b2 = (int)fminf(fmaxf(rintf(v.z/ws),-1.f),1.f);
        int b3 = (int)fminf(fmaxf(rintf(v.w/ws),-1.f),1.f);
        q[j*4 + c4] = (b0&0xff) | ((b1&0xff)<<8) | ((b2&0xff)<<16) | ((b3&0xff)<<24);
    }
}

// ---------------- activation quantization -> int8 + per-row scale ----------------
__global__ __launch_bounds__(256) void quant_x_i8(const float* __restrict__ x,
                                                  char* __restrict__ xq8,
                                                  float* __restrict__ srow){
    int row = blockIdx.x;
    int tid = threadIdx.x;
    const float* p = x + (size_t)row*DIM;
    float4 v = *(const float4*)(p + tid*4);
    float m = fmaxf(fmaxf(fabsf(v.x),fabsf(v.y)), fmaxf(fabsf(v.z),fabsf(v.w)));
    m = wave_max(m);
    __shared__ float red[4];
    if ((tid&63)==0) red[tid>>6] = m;
    __syncthreads();
    m = fmaxf(fmaxf(red[0],red[1]), fmaxf(red[2],red[3]));
    float s = 127.f/(m+1e-5f);
    int a0 = (int)fminf(fmaxf(rintf(v.x*s),-128.f),127.f);
    int a1 = (int)fminf(fmaxf(rintf(v.y*s),-128.f),127.f);
    int a2 = (int)fminf(fmaxf(rintf(v.z*s),-128.f),127.f);
    int a3 = (int)fminf(fmaxf(rintf(v.w*s),-128.f),127.f);
    int pk = (a0&0xff) | ((a1&0xff)<<8) | ((a2&0xff)<<16) | ((a3&0xff)<<24);
    ((int*)xq8)[(size_t)row*256 + tid] = pk;
    if (tid==0) srow[row] = s;
}

// ---------------- int8 MFMA GEMM, double-buffered over quant groups ----------------
__global__ __launch_bounds__(256) void gemm_i8(const char* __restrict__ A8,
                                               const char* __restrict__ W8,
                                               const float* __restrict__ wsb,
                                               const float* __restrict__ srow,
                                               float* __restrict__ C){
    __shared__ __align__(16) char As[2][16384];
    __shared__ __align__(16) char Bs[2][16384];
    int tid = threadIdx.x;
    int w = tid >> 6, lane = tid & 63;
    int wm = w >> 1, wn = w & 1;
    int m0 = blockIdx.y*128, n0 = blockIdx.x*128;
    int l31 = lane & 31, lh = lane >> 5;

    float wsr[2][8];
    #pragma unroll
    for(int jt=0; jt<2; jt++){
        int col = n0 + wn*64 + jt*32 + l31;
        float4 q0 = *(const float4*)(wsb + (size_t)col*8);
        float4 q1 = *(const float4*)(wsb + (size_t)col*8 + 4);
        wsr[jt][0]=q0.x; wsr[jt][1]=q0.y; wsr[jt][2]=q0.z; wsr[jt][3]=q0.w;
        wsr[jt][4]=q1.x; wsr[jt][5]=q1.y; wsr[jt][6]=q1.z; wsr[jt][7]=q1.w;
    }

    float facc[2][2][16];
    #pragma unroll
    for(int a=0;a<2;a++)
        #pragma unroll
        for(int b=0;b<2;b++)
            #pragma unroll
            for(int r=0;r<16;r++) facc[a][b][r]=0.f;

    int srow8 = lane >> 3;
    int scol  = (lane&7) ^ ((lane>>3)&7);
    const char* Ab = A8 + (size_t)m0*1024;
    const char* Bb = W8 + (size_t)n0*1024;

    // prologue: stage group 0 into buffer 0
    {
        if (w < 2){
            #pragma unroll
            for(int r=0;r<8;r++){
                int Wi = w*8 + r;
                gload16(Ab + (size_t)(Wi*8 + srow8)*1024 + scol*16, As[0] + Wi*1024);
            }
        } else {
            #pragma unroll
            for(int r=0;r<8;r++){
                int Wi = (w-2)*8 + r;
                gload16(Bb + (size_t)(Wi*8 + srow8)*1024 + scol*16, Bs[0] + Wi*1024);
            }
        }
    }

    #pragma unroll
    for(int g=0; g<8; g++){
        __syncthreads();   // drains loads for buf g&1; readers of buf (g+1)&1 done
        if (g+1 < 8){
            int nb = (g+1)&1;
            if (w < 2){
                #pragma unroll
                for(int r=0;r<8;r++){
                    int Wi = w*8 + r;
                    gload16(Ab + (size_t)(Wi*8 + srow8)*1024 + (g+1)*128 + scol*16, As[nb] + Wi*1024);
                }
            } else {
                #pragma unroll
                for(int r=0;r<8;r++){
                    int Wi = (w-2)*8 + r;
                    gload16(Bb + (size_t)(Wi*8 + srow8)*1024 + (g+1)*128 + scol*16, Bs[nb] + Wi*1024);
                }
            }
        }
        const char* Ac = As[g&1];
        const char* Bc = Bs[g&1];

        i32x16 iacc[2][2];
        iacc[0][0]=zero16(); iacc[0][1]=zero16();
        iacc[1][0]=zero16(); iacc[1][1]=zero16();
        #pragma unroll
        for(int s=0; s<4; s++){
            int cw = s*2 + lh;
            i32x4 af[2], bf[2];
            #pragma unroll
            for(int it=0; it<2; it++){
                int rl = wm*64 + it*32 + l31;
                int entry = rl*8 + (cw ^ (rl&7));
                af[it] = *(const i32x4*)(Ac + entry*16);
            }
            #pragma unroll
            for(int jt=0; jt<2; jt++){
                int rl = wn*64 + jt*32 + l31;
                int entry = rl*8 + (cw ^ (rl&7));
                bf[jt] = *(const i32x4*)(Bc + entry*16);
            }
            #pragma unroll
            for(int it=0; it<2; it++)
                #pragma unroll
                for(int jt=0; jt<2; jt++)
                    iacc[it][jt] = __builtin_amdgcn_mfma_i32_32x32x32_i8(af[it], bf[jt], iacc[it][jt], 0, 0, 0);
        }
        #pragma unroll
        for(int it=0; it<2; it++)
            #pragma unroll
            for(int jt=0; jt<2; jt++)
                #pragma unroll
                for(int r=0;r<16;r++)
                    facc[it][jt][r] += (float)iacc[it][jt][r] * wsr[jt][g];
    }

    #pragma unroll
    for(int it=0; it<2; it++){
        #pragma unroll
        for(int r=0; r<16; r++){
            int rowl = wm*64 + it*32 + (r&3) + 8*(r>>2) + 4*lh;
            float sv = srow[m0 + rowl];
            #pragma unroll
            for(int jt=0; jt<2; jt++){
                int col = n0 + wn*64 + jt*32 + l31;
                C[(size_t)(m0+rowl)*DIM + col] = facc[it][jt][r] / sv;
            }
        }
    }
}

// ---------------- pack Q (row-order bf16) + K (fragment-order bf16) w/ RoPE ----------------
// K fragment order per (bh,kt): entry W = f*128 + c*64 + gg*16 + mm holds
// K[t=kt*64+16f+mm][d=8gg+32c .. +7] as 8 bf16 (16B). 8 KB per tile.
__global__ __launch_bounds__(256) void pack_qk(const float* __restrict__ qb,
                                               const float* __restrict__ kb,
                                               const float* __restrict__ cosb,
                                               const float* __restrict__ sinb,
                                               unsigned short* __restrict__ Qh,
                                               char* __restrict__ Kf){
    int idx = blockIdx.x*blockDim.x + threadIdx.x;  // MROWS*512
    int bt = idx >> 9;
    int r  = idx & 511;
    int h  = r >> 5;
    int p  = r & 31;
    int b  = bt >> 11;
    int t  = bt & (TT-1);
    int bh = b*NH + h;
    float c = cosb[t*32+p], s = sinb[t*32+p];
    size_t src = (size_t)bt*DIM + h*HD + 2*p;
    float q0 = qb[src], q1 = qb[src+1];
    float k0 = kb[src], k1 = kb[src+1];
    float qe = q0*c - q1*s, qo = q0*s + q1*c;
    float ke = k0*c - k1*s, ko = k0*s + k1*c;
    // Q: row-order
    size_t qdst = ((size_t)bh*TT + t)*HD + 2*p;
    *(ushort2*)(Qh + qdst) = make_ushort2(f2bf(qe), f2bf(qo));
    // K: fragment order
    int kt = t >> 6, tl = t & 63;
    int f = tl >> 4, mm = tl & 15;
    int cc = p >> 4, gg = (p >> 2) & 3, j2 = (p & 3)*2;
    size_t kdst = ((size_t)(bh*32 + kt)*512 + f*128 + cc*64 + gg*16 + mm)*16 + j2*2;
    *(ushort2*)(Kf + kdst) = make_ushort2(f2bf(ke), f2bf(ko));
}

// ---------------- pack V: fp32 [b,t,h,d] -> fragment-order V^T tiles ----------------
// entry W = f*128 + c*64 + gg*16 + mm holds V^T[dv=16f+mm][tl=8gg+32c .. +7].
__global__ __launch_bounds__(256) void pack_v(const float* __restrict__ vb,
                                              char* __restrict__ Vf){
    __shared__ float st[64][65];
    int blk = blockIdx.x;            // bh*32 + kt
    int kt = blk & 31;
    int bh = blk >> 5;
    int b  = bh >> 4;
    int h  = bh & 15;
    int tid = threadIdx.x;
    #pragma unroll
    for(int rep=0; rep<16; rep++){
        int idx = rep*256 + tid;
        int tl = idx >> 6, dv = idx & 63;
        st[tl][dv] = vb[(size_t)(b*TT + kt*64 + tl)*DIM + h*HD + dv];
    }
    __syncthreads();
    char* base = Vf + ((size_t)blk*512)*16;
    #pragma unroll
    for(int rep=0; rep<2; rep++){
        int e = rep*256 + tid;
        int f = e >> 7, cc = (e >> 6) & 1, gg = (e >> 4) & 3, mm = e & 15;
        int dv = 16*f + mm;
        int tb = 8*gg + 32*cc;
        unsigned short sh[8];
        #pragma unroll
        for(int j=0;j<8;j++) sh[j] = f2bf(st[tb+j][dv]);
        *(s16x8*)(base + (size_t)e*16) = *(s16x8*)sh;
    }
}

// ---------------- MFMA flash attention v2 ----------------
// Block = 512 thr = 8 waves. Waves 0-3 -> heavy q-tile (31-pr), waves 4-7 ->
// light q-tile (pr); exactly 33 MFMA-wave-iterations per block. K/V staged
// async (global_load_lds 16B, fragment-order global) double-buffered, one
// barrier per tile.
__global__ __launch_bounds__(512) void attn_mfma2(const unsigned short* __restrict__ Qh,
                                                  const char* __restrict__ Kf,
                                                  const char* __restrict__ Vf,
                                                  float* __restrict__ ao){
    __shared__ s16x8 Kbuf[2][512];   // 16 KB
    __shared__ s16x8 Vbuf[2][512];   // 16 KB
    int blk = blockIdx.x;
    int pr = blk & 15;
    int bh = blk >> 4;
    int b  = bh >> 4;
    int tid = threadIdx.x;
    int w = tid >> 6, lane = tid & 63;
    int m = lane & 15, g = lane >> 4;
    int my_qt = (w < 4) ? (31 - pr) : pr;
    int ntiles = 32 - pr;
    int q = my_qt*64 + (w & 3)*16 + m;

    const unsigned short* Qhead = Qh + (size_t)bh*TT*HD;
    const char* Kbase = Kf + (size_t)bh*32*8192;
    const char* Vbase = Vf + (size_t)bh*32*8192;

    s16x8 Qf0 = *(const s16x8*)(Qhead + (size_t)q*HD + g*8);
    s16x8 Qf1 = *(const s16x8*)(Qhead + (size_t)q*HD + g*8 + 32);

    f32x4 Of[4] = {f32x4{0,0,0,0}, f32x4{0,0,0,0}, f32x4{0,0,0,0}, f32x4{0,0,0,0}};
    float mrow = -1e30f, lrow = 0.f;

    // prologue: stage tile 0 into buffer 0 (1 entry each of K,V per thread)
    gload16(Kbase + tid*16, (char*)Kbuf + (tid>>6)*1024);
    gload16(Vbase + tid*16, (char*)Vbuf + (tid>>6)*1024);

    for(int kt=0; kt<ntiles; kt++){
        __syncthreads();   // drains loads for buf kt&1; readers of buf (kt+1)&1 done
        if (kt+1 < ntiles){
            int nb = (kt+1)&1;
            gload16(Kbase + (size_t)(kt+1)*8192 + tid*16, (char*)Kbuf + nb*8192 + (tid>>6)*1024);
            gload16(Vbase + (size_t)(kt+1)*8192 + tid*16, (char*)Vbuf + nb*8192 + (tid>>6)*1024);
        }
        if (kt <= my_qt){
            const s16x8* Kc = Kbuf[kt&1];
            const s16x8* Vc = Vbuf[kt&1];

            f32x4 S[4];
            #pragma unroll
            for(int f=0; f<4; f++){
                s16x8 k0 = Kc[(f*2+0)*64 + lane];
                s16x8 k1 = Kc[(f*2+1)*64 + lane];
                f32x4 acc = {0,0,0,0};
                acc = __builtin_amdgcn_mfma_f32_16x16x32_bf16(k0, Qf0, acc, 0, 0, 0);
                acc = __builtin_amdgcn_mfma_f32_16x16x32_bf16(k1, Qf1, acc, 0, 0, 0);
                S[f] = acc;
            }

            bool diag = (kt == my_qt);
            float p[4][4];
            float mloc = -1e30f;
            #pragma unroll
            for(int f=0; f<4; f++)
                #pragma unroll
                for(int r=0; r<4; r++){
                    float s = S[f][r]*0.125f;
                    if (diag){
                        int key = kt*64 + 16*f + 4*g + r;
                        if (key > q) s = -1e30f;
                    }
                    p[f][r] = s;
                    mloc = fmaxf(mloc, s);
                }
            mloc = fmaxf(mloc, __shfl_xor(mloc, 16));
            mloc = fmaxf(mloc, __shfl_xor(mloc, 32));
            float mn = fmaxf(mrow, mloc);
            float alpha = __expf(mrow - mn);
            float ps = 0.f;
            #pragma unroll
            for(int f=0; f<4; f++)
                #pragma unroll
                for(int r=0; r<4; r++){
                    float e = __expf(p[f][r] - mn);
                    p[f][r] = e;
                    ps += e;
                }
            ps += __shfl_xor(ps, 16);
            ps += __shfl_xor(ps, 32);
            lrow = lrow*alpha + ps;
            mrow = mn;

            #pragma unroll
            for(int f2=0; f2<4; f2++)
                #pragma unroll
                for(int r=0; r<4; r++) Of[f2][r] *= alpha;

            unsigned pp0[4], pp1[4];
            #pragma unroll
            for(int f=0; f<4; f++){
                pp0[f] = (unsigned)f2bf(p[f][0]) | ((unsigned)f2bf(p[f][1]) << 16);
                pp1[f] = (unsigned)f2bf(p[f][2]) | ((unsigned)f2bf(p[f][3]) << 16);
            }

            int src0 = m + 16*(2*(g&1));
            int src1 = src0 + 16;
            bool hi = (g >= 2);
            #pragma unroll
            for(int c=0; c<2; c++){
                unsigned a0 = (unsigned)__shfl((int)pp0[2*c],   src0);
                unsigned a1 = (unsigned)__shfl((int)pp0[2*c+1], src0);
                unsigned b0 = hi ? a1 : a0;
                unsigned a2 = (unsigned)__shfl((int)pp1[2*c],   src0);
                unsigned a3 = (unsigned)__shfl((int)pp1[2*c+1], src0);
                unsigned b1 = hi ? a3 : a2;
                unsigned a4 = (unsigned)__shfl((int)pp0[2*c],   src1);
                unsigned a5 = (unsigned)__shfl((int)pp0[2*c+1], src1);
                unsigned b2 = hi ? a5 : a4;
                unsigned a6 = (unsigned)__shfl((int)pp1[2*c],   src1);
                unsigned a7 = (unsigned)__shfl((int)pp1[2*c+1], src1);
                unsigned b3 = hi ? a7 : a6;
                union { unsigned u[4]; s16x8 v; } Bf;
                Bf.u[0]=b0; Bf.u[1]=b1; Bf.u[2]=b2; Bf.u[3]=b3;
                #pragma unroll
                for(int f2=0; f2<4; f2++){
                    s16x8 vf = Vc[(f2*2+c)*64 + lane];
                    Of[f2] = __builtin_amdgcn_mfma_f32_16x16x32_bf16(vf, Bf.v, Of[f2], 0, 0, 0);
                }
            }
        }
    }

    float invl = 1.0f / lrow;
    size_t obase = (size_t)(b*TT + q)*DIM + (bh & 15)*HD;
    #pragma unroll
    for(int f2=0; f2<4; f2++)
        #pragma unroll
        for(int r=0; r<4; r++)
            ao[obase + 16*f2 + 4*g + r] = Of[f2][r]*invl;
}

// ---------------- launch ----------------
extern "C" void kernel_launch(void* const* d_in, const int* in_sizes, int n_in,
                              void* d_out, int out_size, void* d_ws, size_t ws_size,
                              hipStream_t stream){
    const float* x    = (const float*)d_in[0];
    const float* cosb = (const float*)d_in[1];
    const float* sinb = (const float*)d_in[2];
    const float* wq_w = (const float*)d_in[3];
    const float* wk_w = (const float*)d_in[4];
    const float* wv_w = (const float*)d_in[5];
    const float* wo_w = (const float*)d_in[6];
    float* out = (float*)d_out;

    float* f = (float*)d_ws;
    char*  cw = (char*)d_ws;
    const size_t MB = 1048576;
    // byte layout (77 MB total, same footprint as round 3):
    char*  w8all = cw;                           // [0,4MB)   ternary weights x4
    float* wsall = (float*)(cw + 4*MB);          // [4,4.25MB) scales 4x8192
    float* srow1 = wsall + 4*8192;
    float* srow2 = srow1 + 4096;
    char*  xq8   = cw + 5*MB;                    // [5,9MB)
    char*  xq8_2 = cw + 9*MB;                    // [9,13MB)
    float* qb    = (float*)(cw + 13*MB);         // [13,29MB)
    float* kb    = (float*)(cw + 29*MB);         // [29,45MB)
    float* vb    = (float*)(cw + 45*MB);         // [45,61MB)
    unsigned short* Qh = (unsigned short*)(cw + 61*MB);  // [61,69MB)
    char*  Kf    = cw + 69*MB;                   // [69,77MB)
    char*  Vf    = cw + 13*MB;                   // alias qb (dead after pack_qk)
    float* ao    = kb;                           // alias kb (dead after pack_qk)

    quant_w4<<<1024, 256, 0, stream>>>(wq_w, wk_w, wv_w, wo_w, w8all, wsall);
    quant_x_i8<<<MROWS, 256, 0, stream>>>(x, xq8, srow1);

    dim3 gg(DIM/128, MROWS/128);   // (8, 32)
    gemm_i8<<<gg, 256, 0, stream>>>(xq8, w8all + 0*MB, wsall + 0*8192, srow1, qb);
    gemm_i8<<<gg, 256, 0, stream>>>(xq8, w8all + 1*MB, wsall + 1*8192, srow1, kb);
    gemm_i8<<<gg, 256, 0, stream>>>(xq8, w8all + 2*MB, wsall + 2*8192, srow1, vb);

    pack_qk<<<(MROWS*512)/256, 256, 0, stream>>>(qb, kb, cosb, sinb, Qh, Kf);
    pack_v<<<BB*NH*(TT/64), 256, 0, stream>>>(vb, Vf);

    attn_mfma2<<<512, 512, 0, stream>>>(Qh, Kf, Vf, ao);

    quant_x_i8<<<MROWS, 256, 0, stream>>>(ao, xq8_2, srow2);
    gemm_i8<<<gg, 256, 0, stream>>>(xq8_2, w8all + 3*MB, wsall + 3*8192, srow2, out);
}

// Round 5
// 248.023 us; speedup vs baseline: 7.7942x; 1.0531x over previous
//
#include <hip/hip_runtime.h>
#include <math.h>

#define DIM   1024
#define NH    16
#define HD    64
#define GRP   128
#define BB    2
#define TT    2048
#define MROWS (BB*TT)   // 4096

typedef __attribute__((ext_vector_type(8))) short s16x8;
typedef __attribute__((ext_vector_type(4))) float f32x4;
typedef __attribute__((ext_vector_type(4))) int   i32x4;
typedef __attribute__((ext_vector_type(16))) int  i32x16;

__device__ inline float wave_max(float v){
    for(int off=32; off; off>>=1) v = fmaxf(v, __shfl_xor(v, off));
    return v;
}

__device__ inline unsigned short f2bf(float x){
    union { float f; unsigned u; } v; v.f = x;
    unsigned r = v.u + 0x7fffu + ((v.u >> 16) & 1u);
    return (unsigned short)(r >> 16);
}

// packed f32x2 -> bf16x2 (RTNE), single instruction when available
#if __has_builtin(__builtin_amdgcn_cvt_pk_bf16_f32)
typedef __bf16 bf16x2 __attribute__((ext_vector_type(2)));
__device__ inline unsigned pk2(float a, float b){
    union { bf16x2 v; unsigned u; } c;
    c.v = __builtin_amdgcn_cvt_pk_bf16_f32(a, b);
    return c.u;
}
#else
__device__ inline unsigned pk2(float a, float b){
    return (unsigned)f2bf(a) | ((unsigned)f2bf(b) << 16);
}
#endif

#if __has_builtin(__builtin_amdgcn_exp2f)
__device__ inline float fexp2(float x){ return __builtin_amdgcn_exp2f(x); }
#else
__device__ inline float fexp2(float x){ return exp2f(x); }
#endif

__device__ inline i32x16 zero16(){
    i32x16 z;
    #pragma unroll
    for(int i=0;i<16;i++) z[i]=0;
    return z;
}

__device__ inline void gload16(const void* g, void* l){
    __builtin_amdgcn_global_load_lds((const __attribute__((address_space(1))) unsigned int*)g,
                                     (__attribute__((address_space(3))) unsigned int*)l, 16, 0, 0);
}

// ---------------- fused weight quantization: 8 lanes per group ----------------
__global__ __launch_bounds__(256) void quant_w4(const float* __restrict__ w0,
                                                const float* __restrict__ w1,
                                                const float* __restrict__ w2,
                                                const float* __restrict__ w3,
                                                char* __restrict__ w8,
                                                float* __restrict__ wsall){
    int blk = blockIdx.x;             // 1024 blocks
    int widx = blk >> 8;
    const float* w = (widx==0)?w0 : (widx==1)?w1 : (widx==2)?w2 : w3;
    int tid = threadIdx.x;
    int gloc = (blk & 255)*32 + (tid >> 3);   // group 0..8191
    int j = tid & 7;
    const float* p = w + (size_t)gloc*GRP;
    float r = 0.f;
    #pragma unroll
    for(int i=0;i<16;i++) r += fabsf(p[8*i + j]);
    r += __shfl_xor(r, 1);
    r += __shfl_xor(r, 2);
    r += __shfl_xor(r, 4);
    float ws = r/(float)GRP + 1e-5f;
    if (j == 0) wsall[widx*8192 + gloc] = ws;
    int* q = (int*)(w8 + (size_t)widx*1048576 + (size_t)gloc*GRP);
    int i0 = j*16;
    #pragma unroll
    for(int c4=0;c4<4;c4++){
        float4 v = *(const float4*)(p + i0 + c4*4);
        int b0 = (int)fminf(fmaxf(rintf(v.x/ws),-1.f),1.f);
        int b1 = (int)fminf(fmaxf(rintf(v.y/ws),-1.f),1.f);
        int b2 = (int)fminf(fmaxf(rintf(v.z/ws),-1.f),1.f);
        int b3 = (int)fminf(fmaxf(rintf(v.w/ws),-1.f),1.f);
        q[j*4 + c4] = (b0&0xff) | ((b1&0xff)<<8) | ((b2&0xff)<<16) | ((b3&0xff)<<24);
    }
}

// ---------------- activation quantization -> int8 + per-row scale ----------------
__global__ __launch_bounds__(256) void quant_x_i8(const float* __restrict__ x,
                                                  char* __restrict__ xq8,
                                                  float* __restrict__ srow){
    int row = blockIdx.x;
    int tid = threadIdx.x;
    const float* p = x + (size_t)row*DIM;
    float4 v = *(const float4*)(p + tid*4);
    float m = fmaxf(fmaxf(fabsf(v.x),fabsf(v.y)), fmaxf(fabsf(v.z),fabsf(v.w)));
    m = wave_max(m);
    __shared__ float red[4];
    if ((tid&63)==0) red[tid>>6] = m;
    __syncthreads();
    m = fmaxf(fmaxf(red[0],red[1]), fmaxf(red[2],red[3]));
    float s = 127.f/(m+1e-5f);
    int a0 = (int)fminf(fmaxf(rintf(v.x*s),-128.f),127.f);
    int a1 = (int)fminf(fmaxf(rintf(v.y*s),-128.f),127.f);
    int a2 = (int)fminf(fmaxf(rintf(v.z*s),-128.f),127.f);
    int a3 = (int)fminf(fmaxf(rintf(v.w*s),-128.f),127.f);
    int pk = (a0&0xff) | ((a1&0xff)<<8) | ((a2&0xff)<<16) | ((a3&0xff)<<24);
    ((int*)xq8)[(size_t)row*256 + tid] = pk;
    if (tid==0) srow[row] = s;
}

// ---------------- int8 MFMA GEMM v2: 64x128 tile, 2-3 blocks/CU, dbuf ----------------
// 4 waves; wave w: m-tile wm=w&1 (32 rows), n-tiles (w>>1)*2+{0,1} (2x32 cols).
__global__ __launch_bounds__(256) void gemm_i8(const char* __restrict__ A8,
                                               const char* __restrict__ W8,
                                               const float* __restrict__ wsb,
                                               const float* __restrict__ srow,
                                               float* __restrict__ C){
    __shared__ __align__(16) char As[2][8192];
    __shared__ __align__(16) char Bs[2][16384];
    int tid = threadIdx.x;
    int w = tid >> 6, lane = tid & 63;
    int wm = w & 1, wn = w >> 1;
    int m0 = blockIdx.y*64, n0 = blockIdx.x*128;
    int l31 = lane & 31, lh = lane >> 5;

    float wsr[2][8];
    #pragma unroll
    for(int jt=0; jt<2; jt++){
        int col = n0 + (wn*2+jt)*32 + l31;
        float4 q0 = *(const float4*)(wsb + (size_t)col*8);
        float4 q1 = *(const float4*)(wsb + (size_t)col*8 + 4);
        wsr[jt][0]=q0.x; wsr[jt][1]=q0.y; wsr[jt][2]=q0.z; wsr[jt][3]=q0.w;
        wsr[jt][4]=q1.x; wsr[jt][5]=q1.y; wsr[jt][6]=q1.z; wsr[jt][7]=q1.w;
    }

    float facc[2][16];
    #pragma unroll
    for(int b=0;b<2;b++)
        #pragma unroll
        for(int r=0;r<16;r++) facc[b][r]=0.f;

    int row8 = lane >> 3;
    int scw  = (lane&7) ^ ((lane>>3)&7);
    const char* Ab = A8 + (size_t)m0*1024;
    const char* Bb = W8 + (size_t)n0*1024;

    // stage group 0 into buffer 0
    {
        #pragma unroll
        for(int r=0;r<2;r++){
            int j = w*2 + r;      // A inst 0..7
            gload16(Ab + (size_t)(j*8 + row8)*1024 + scw*16, As[0] + j*1024);
        }
        #pragma unroll
        for(int r=0;r<4;r++){
            int j = w*4 + r;      // B inst 0..15
            gload16(Bb + (size_t)(j*8 + row8)*1024 + scw*16, Bs[0] + j*1024);
        }
    }

    #pragma unroll
    for(int g=0; g<8; g++){
        __syncthreads();   // drains loads for buf g&1
        if (g+1 < 8){
            int nb = (g+1)&1;
            #pragma unroll
            for(int r=0;r<2;r++){
                int j = w*2 + r;
                gload16(Ab + (size_t)(j*8 + row8)*1024 + (g+1)*128 + scw*16, As[nb] + j*1024);
            }
            #pragma unroll
            for(int r=0;r<4;r++){
                int j = w*4 + r;
                gload16(Bb + (size_t)(j*8 + row8)*1024 + (g+1)*128 + scw*16, Bs[nb] + j*1024);
            }
        }
        const char* Ac = As[g&1];
        const char* Bc = Bs[g&1];

        i32x16 iacc[2];
        iacc[0]=zero16(); iacc[1]=zero16();
        #pragma unroll
        for(int s=0; s<4; s++){
            int cw = s*2 + lh;
            int rlA = wm*32 + l31;
            i32x4 afr = *(const i32x4*)(Ac + (rlA*8 + (cw ^ (rlA&7)))*16);
            #pragma unroll
            for(int jt=0; jt<2; jt++){
                int rlB = (wn*2+jt)*32 + l31;
                i32x4 bfr = *(const i32x4*)(Bc + (rlB*8 + (cw ^ (rlB&7)))*16);
                iacc[jt] = __builtin_amdgcn_mfma_i32_32x32x32_i8(afr, bfr, iacc[jt], 0, 0, 0);
            }
        }
        #pragma unroll
        for(int jt=0; jt<2; jt++)
            #pragma unroll
            for(int r=0;r<16;r++)
                facc[jt][r] += (float)iacc[jt][r] * wsr[jt][g];
    }

    #pragma unroll
    for(int r=0; r<16; r++){
        int rowl = wm*32 + (r&3) + 8*(r>>2) + 4*lh;
        float sv = srow[m0 + rowl];
        #pragma unroll
        for(int jt=0; jt<2; jt++){
            int col = n0 + (wn*2+jt)*32 + l31;
            C[(size_t)(m0+rowl)*DIM + col] = facc[jt][r] / sv;
        }
    }
}

// ---------------- pack Q (row-order bf16, PRE-SCALED by 0.125*log2e) + K (frag-order) ----------------
#define QSC 0.18033688011112042f   // 0.125 * log2(e)
__global__ __launch_bounds__(256) void pack_qk(const float* __restrict__ qb,
                                               const float* __restrict__ kb,
                                               const float* __restrict__ cosb,
                                               const float* __restrict__ sinb,
                                               unsigned short* __restrict__ Qh,
                                               char* __restrict__ Kf){
    int idx = blockIdx.x*blockDim.x + threadIdx.x;  // MROWS*512
    int bt = idx >> 9;
    int r  = idx & 511;
    int h  = r >> 5;
    int p  = r & 31;
    int b  = bt >> 11;
    int t  = bt & (TT-1);
    int bh = b*NH + h;
    float c = cosb[t*32+p], s = sinb[t*32+p];
    size_t src = (size_t)bt*DIM + h*HD + 2*p;
    float q0 = qb[src], q1 = qb[src+1];
    float k0 = kb[src], k1 = kb[src+1];
    float qe = (q0*c - q1*s)*QSC, qo = (q0*s + q1*c)*QSC;
    float ke = k0*c - k1*s,       ko = k0*s + k1*c;
    size_t qdst = ((size_t)bh*TT + t)*HD + 2*p;
    *(ushort2*)(Qh + qdst) = make_ushort2(f2bf(qe), f2bf(qo));
    int kt = t >> 6, tl = t & 63;
    int f = tl >> 4, mm = tl & 15;
    int cc = p >> 4, gg = (p >> 2) & 3, j2 = (p & 3)*2;
    size_t kdst = ((size_t)(bh*32 + kt)*512 + f*128 + cc*64 + gg*16 + mm)*16 + j2*2;
    *(ushort2*)(Kf + kdst) = make_ushort2(f2bf(ke), f2bf(ko));
}

// ---------------- pack V: fp32 [b,t,h,d] -> fragment-order V^T tiles ----------------
__global__ __launch_bounds__(256) void pack_v(const float* __restrict__ vb,
                                              char* __restrict__ Vf){
    __shared__ float st[64][65];
    int blk = blockIdx.x;            // bh*32 + kt
    int kt = blk & 31;
    int bh = blk >> 5;
    int b  = bh >> 4;
    int h  = bh & 15;
    int tid = threadIdx.x;
    #pragma unroll
    for(int rep=0; rep<16; rep++){
        int idx = rep*256 + tid;
        int tl = idx >> 6, dv = idx & 63;
        st[tl][dv] = vb[(size_t)(b*TT + kt*64 + tl)*DIM + h*HD + dv];
    }
    __syncthreads();
    char* base = Vf + ((size_t)blk*512)*16;
    #pragma unroll
    for(int rep=0; rep<2; rep++){
        int e = rep*256 + tid;
        int f = e >> 7, cc = (e >> 6) & 1, gg = (e >> 4) & 3, mm = e & 15;
        int dv = 16*f + mm;
        int tb = 8*gg + 32*cc;
        unsigned short sh[8];
        #pragma unroll
        for(int j=0;j<8;j++) sh[j] = f2bf(st[tb+j][dv]);
        *(s16x8*)(base + (size_t)e*16) = *(s16x8*)sh;
    }
}

// ---------------- MFMA flash attention v3 ----------------
// 1024 blocks x 256 thr (4 waves), one q-tile (64 rows) per block, globally
// heavy-first. K/V async dbuf (one barrier/tile). Q pre-scaled -> exp2 path.
__global__ __launch_bounds__(256) void attn_mfma3(const unsigned short* __restrict__ Qh,
                                                  const char* __restrict__ Kf,
                                                  const char* __restrict__ Vf,
                                                  float* __restrict__ ao){
    __shared__ s16x8 Kbuf[2][512];   // 16 KB
    __shared__ s16x8 Vbuf[2][512];   // 16 KB
    int blk = blockIdx.x;
    int qt = 31 - (blk >> 5);        // heavy first across the whole grid
    int bh = blk & 31;
    int b  = bh >> 4;
    int tid = threadIdx.x;
    int w = tid >> 6, lane = tid & 63;
    int m = lane & 15, g = lane >> 4;
    int q = qt*64 + w*16 + m;

    const unsigned short* Qhead = Qh + (size_t)bh*TT*HD;
    const char* Kbase = Kf + (size_t)bh*32*8192;
    const char* Vbase = Vf + (size_t)bh*32*8192;

    s16x8 Qf0 = *(const s16x8*)(Qhead + (size_t)q*HD + g*8);
    s16x8 Qf1 = *(const s16x8*)(Qhead + (size_t)q*HD + g*8 + 32);

    f32x4 Of[4] = {f32x4{0,0,0,0}, f32x4{0,0,0,0}, f32x4{0,0,0,0}, f32x4{0,0,0,0}};
    float mrow = -1e30f, lrow = 0.f;

    // stage tile 0 into buffer 0: 2 K insts + 2 V insts per wave
    #pragma unroll
    for(int r=0;r<2;r++){
        gload16(Kbase + ((r*4 + w)*64 + lane)*16, (char*)Kbuf[0] + (r*4 + w)*1024);
        gload16(Vbase + ((r*4 + w)*64 + lane)*16, (char*)Vbuf[0] + (r*4 + w)*1024);
    }

    for(int kt=0; kt<=qt; kt++){
        __syncthreads();   // drains loads for buf kt&1
        if (kt < qt){
            int nb = (kt+1)&1;
            size_t goff = (size_t)(kt+1)*8192;
            #pragma unroll
            for(int r=0;r<2;r++){
                gload16(Kbase + goff + ((r*4 + w)*64 + lane)*16, (char*)Kbuf[nb] + (r*4 + w)*1024);
                gload16(Vbase + goff + ((r*4 + w)*64 + lane)*16, (char*)Vbuf[nb] + (r*4 + w)*1024);
            }
        }
        const s16x8* Kc = Kbuf[kt&1];
        const s16x8* Vc = Vbuf[kt&1];

        f32x4 S[4];
        #pragma unroll
        for(int f=0; f<4; f++){
            s16x8 k0 = Kc[(f*2+0)*64 + lane];
            s16x8 k1 = Kc[(f*2+1)*64 + lane];
            f32x4 acc = {0,0,0,0};
            acc = __builtin_amdgcn_mfma_f32_16x16x32_bf16(k0, Qf0, acc, 0, 0, 0);
            acc = __builtin_amdgcn_mfma_f32_16x16x32_bf16(k1, Qf1, acc, 0, 0, 0);
            S[f] = acc;
        }

        // online softmax in base-2 domain (Q pre-scaled by 0.125*log2e)
        float p[4][4];
        float mloc = -1e30f;
        if (kt == qt){
            #pragma unroll
            for(int f=0; f<4; f++)
                #pragma unroll
                for(int r=0; r<4; r++){
                    int key = 16*f + 4*g + r;
                    float s = (qt*64 + key > q) ? -1e30f : S[f][r];
                    p[f][r] = s;
                    mloc = fmaxf(mloc, s);
                }
        } else {
            #pragma unroll
            for(int f=0; f<4; f++)
                #pragma unroll
                for(int r=0; r<4; r++){
                    p[f][r] = S[f][r];
                    mloc = fmaxf(mloc, S[f][r]);
                }
        }
        mloc = fmaxf(mloc, __shfl_xor(mloc, 16));
        mloc = fmaxf(mloc, __shfl_xor(mloc, 32));
        float mn = fmaxf(mrow, mloc);
        float alpha = fexp2(mrow - mn);
        float ps = 0.f;
        #pragma unroll
        for(int f=0; f<4; f++)
            #pragma unroll
            for(int r=0; r<4; r++){
                float e = fexp2(p[f][r] - mn);
                p[f][r] = e;
                ps += e;
            }
        ps += __shfl_xor(ps, 16);
        ps += __shfl_xor(ps, 32);
        lrow = lrow*alpha + ps;
        mrow = mn;

        #pragma unroll
        for(int f2=0; f2<4; f2++)
            #pragma unroll
            for(int r=0; r<4; r++) Of[f2][r] *= alpha;

        unsigned pp0[4], pp1[4];
        #pragma unroll
        for(int f=0; f<4; f++){
            pp0[f] = pk2(p[f][0], p[f][1]);
            pp1[f] = pk2(p[f][2], p[f][3]);
        }

        int src0 = m + 16*(2*(g&1));
        int src1 = src0 + 16;
        bool hi = (g >= 2);
        #pragma unroll
        for(int c=0; c<2; c++){
            unsigned a0 = (unsigned)__shfl((int)pp0[2*c],   src0);
            unsigned a1 = (unsigned)__shfl((int)pp0[2*c+1], src0);
            unsigned b0 = hi ? a1 : a0;
            unsigned a2 = (unsigned)__shfl((int)pp1[2*c],   src0);
            unsigned a3 = (unsigned)__shfl((int)pp1[2*c+1], src0);
            unsigned b1 = hi ? a3 : a2;
            unsigned a4 = (unsigned)__shfl((int)pp0[2*c],   src1);
            unsigned a5 = (unsigned)__shfl((int)pp0[2*c+1], src1);
            unsigned b2 = hi ? a5 : a4;
            unsigned a6 = (unsigned)__shfl((int)pp1[2*c],   src1);
            unsigned a7 = (unsigned)__shfl((int)pp1[2*c+1], src1);
            unsigned b3 = hi ? a7 : a6;
            union { unsigned u[4]; s16x8 v; } Bf;
            Bf.u[0]=b0; Bf.u[1]=b1; Bf.u[2]=b2; Bf.u[3]=b3;
            #pragma unroll
            for(int f2=0; f2<4; f2++){
                s16x8 vf = Vc[(f2*2+c)*64 + lane];
                Of[f2] = __builtin_amdgcn_mfma_f32_16x16x32_bf16(vf, Bf.v, Of[f2], 0, 0, 0);
            }
        }
    }

    float invl = 1.0f / lrow;
    size_t obase = (size_t)(b*TT + q)*DIM + (bh & 15)*HD;
    #pragma unroll
    for(int f2=0; f2<4; f2++)
        #pragma unroll
        for(int r=0; r<4; r++)
            ao[obase + 16*f2 + 4*g + r] = Of[f2][r]*invl;
}

// ---------------- launch ----------------
extern "C" void kernel_launch(void* const* d_in, const int* in_sizes, int n_in,
                              void* d_out, int out_size, void* d_ws, size_t ws_size,
                              hipStream_t stream){
    const float* x    = (const float*)d_in[0];
    const float* cosb = (const float*)d_in[1];
    const float* sinb = (const float*)d_in[2];
    const float* wq_w = (const float*)d_in[3];
    const float* wk_w = (const float*)d_in[4];
    const float* wv_w = (const float*)d_in[5];
    const float* wo_w = (const float*)d_in[6];
    float* out = (float*)d_out;

    char*  cw = (char*)d_ws;
    const size_t MB = 1048576;
    char*  w8all = cw;                           // [0,4MB)
    float* wsall = (float*)(cw + 4*MB);          // [4,4.25MB)
    float* srow1 = wsall + 4*8192;
    float* srow2 = srow1 + 4096;
    char*  xq8   = cw + 5*MB;                    // [5,9MB)
    char*  xq8_2 = cw + 9*MB;                    // [9,13MB)
    float* qb    = (float*)(cw + 13*MB);         // [13,29MB)
    float* kb    = (float*)(cw + 29*MB);         // [29,45MB)
    float* vb    = (float*)(cw + 45*MB);         // [45,61MB)
    unsigned short* Qh = (unsigned short*)(cw + 61*MB);  // [61,69MB)
    char*  Kf    = cw + 69*MB;                   // [69,77MB)
    char*  Vf    = cw + 13*MB;                   // alias qb (dead after pack_qk)
    float* ao    = kb;                           // alias kb (dead after pack_qk)

    quant_w4<<<1024, 256, 0, stream>>>(wq_w, wk_w, wv_w, wo_w, w8all, wsall);
    quant_x_i8<<<MROWS, 256, 0, stream>>>(x, xq8, srow1);

    dim3 gg(DIM/128, MROWS/64);   // (8, 64) = 512 blocks
    gemm_i8<<<gg, 256, 0, stream>>>(xq8, w8all + 0*MB, wsall + 0*8192, srow1, qb);
    gemm_i8<<<gg, 256, 0, stream>>>(xq8, w8all + 1*MB, wsall + 1*8192, srow1, kb);
    gemm_i8<<<gg, 256, 0, stream>>>(xq8, w8all + 2*MB, wsall + 2*8192, srow1, vb);

    pack_qk<<<(MROWS*512)/256, 256, 0, stream>>>(qb, kb, cosb, sinb, Qh, Kf);
    pack_v<<<BB*NH*(TT/64), 256, 0, stream>>>(vb, Vf);

    attn_mfma3<<<1024, 256, 0, stream>>>(Qh, Kf, Vf, ao);

    quant_x_i8<<<MROWS, 256, 0, stream>>>(ao, xq8_2, srow2);
    gemm_i8<<<gg, 256, 0, stream>>>(xq8_2, w8all + 3*MB, wsall + 3*8192, srow2, out);
}